// Round 10
// baseline (44.906 us; speedup 1.0000x reference)
//
#include <hip/hip_runtime.h>
#include <hip/hip_bf16.h>
#include <stdint.h>

// Problem geometry
#define NB 64          // batch
#define NC 64          // C_IN
#define NU 2048        // N_UNITS
#define K_REAL 1296    // H*W = 36*36
#define K_PAD  1344    // 42 ks-steps of 32 (3.7% pad)
#define M_ROWS 4096    // NB*NC

// GEMM tile
#define BM 256
#define BN 128
#define NKS 42         // 32-wide K-steps

typedef __attribute__((ext_vector_type(4))) float f32x4;
typedef __attribute__((ext_vector_type(8))) short bf16x8;

__device__ __forceinline__ unsigned short f2bf_rne(float f) {
  union { float f; uint32_t u; } v; v.f = f;
  uint32_t u = v.u;
  return (unsigned short)((u + 0x7FFFu + ((u >> 16) & 1u)) >> 16);
}

// Convert fp32 [rows][K_REAL] -> bf16 [rows][K_PAD], zero-filling the pad
// tail. Handles BOTH x (rows 0..4095) and sw (rows 4096..6143) in one launch.
__global__ void convert_pad_kernel(const float* __restrict__ x,
                                   const float* __restrict__ sw,
                                   unsigned short* __restrict__ dst) {
  const int KB = K_PAD / 8;  // 168 8-element blocks per row
  const int total = (M_ROWS + NU) * KB;
  for (int idx = blockIdx.x * blockDim.x + threadIdx.x; idx < total;
       idx += gridDim.x * blockDim.x) {
    int r  = idx / KB;
    int kb = idx - r * KB;
    int k0 = kb * 8;
    uint32_t p0 = 0, p1 = 0, p2 = 0, p3 = 0;
    if (k0 + 8 <= K_REAL) {  // K_REAL % 8 == 0: blocks are all-real or all-pad
      const float* srow = (r < M_ROWS) ? (x + (size_t)r * K_REAL)
                                       : (sw + (size_t)(r - M_ROWS) * K_REAL);
      const float4* s = (const float4*)(srow + k0);
      float4 f0 = s[0];
      float4 f1 = s[1];
      p0 = (uint32_t)f2bf_rne(f0.x) | ((uint32_t)f2bf_rne(f0.y) << 16);
      p1 = (uint32_t)f2bf_rne(f0.z) | ((uint32_t)f2bf_rne(f0.w) << 16);
      p2 = (uint32_t)f2bf_rne(f1.x) | ((uint32_t)f2bf_rne(f1.y) << 16);
      p3 = (uint32_t)f2bf_rne(f1.z) | ((uint32_t)f2bf_rne(f1.w) << 16);
    }
    uint4 o; o.x = p0; o.y = p1; o.z = p2; o.w = p3;
    *(uint4*)(dst + (size_t)r * K_PAD + k0) = o;
  }
}

// ---------------------------------------------------------------------------
// 256x128 fused GEMM, ring-of-5 ks-slot pipeline — DEPINNED (R10).
// Identical geometry/swizzle/epilogue to R9; the only change is removal of
// every __builtin_amdgcn_sched_barrier(0) (m141: order-pinning defeats the
// compiler scheduler) and explicit lgkmcnt (plain-typed LDS loads -> the
// compiler tracks the MFMA dependency and inserts exact counts itself).
// Phase s: { stage ks s+4 into slot (s+4)%5 | ds_read frags slot s%5
//            -> s_barrier -> 16 MFMA (setprio) -> vmcnt(9) -> s_barrier }.
// Safety (audited): slot (s+4)%5 was last read in phase s-1, whose reads
// drain before its closing barrier; this stage issues after that barrier;
// side-effecting intrinsics (barrier, global_load_lds) don't reorder.
// vmcnt(9) at phase s-1 exactly guarantees slot-s's 3 loads landed (9 newer
// loads outstanding from phases s-3..s-1), and its "memory" clobber stops
// the next LDFRAGS hoisting above it. Tail: VMW 9,9,9,6,3,0.
// ---------------------------------------------------------------------------
__global__ __launch_bounds__(512, 1)
void fused_readout_gemm(const unsigned short* __restrict__ Abf,  // [M_ROWS][K_PAD]
                        const unsigned short* __restrict__ Bbf,  // [NU][K_PAD]
                        const float* __restrict__ fw,            // [NU][NC]
                        const float* __restrict__ bias,          // [NU]
                        float* __restrict__ out) {               // [NB][NU]
  __shared__ unsigned short As[5][8192];  // slot: 256 rows x 32 (16KB)
  __shared__ unsigned short Bs[5][4096];  // slot: 128 rows x 32 (8KB)

  const int tid  = threadIdx.x;
  const int lane = tid & 63;
  const int w    = tid >> 6;    // 0..7
  const int wm   = w >> 1;      // 0..3: 64-row group (one batch each)
  const int wn   = w & 1;       // 0..1: 64-col group
  const int g    = lane >> 4;   // k-group 0..3
  const int rl   = lane & 15;

  // XCD mapping: xcd = braw&7 owns a 4(tileM) x 8(tileN) rectangle.
  const int braw  = (int)blockIdx.x;
  const int xcd   = braw & 7;
  const int idx   = braw >> 3;           // 0..31
  const int tileM = (xcd >> 1) * 4 + (idx & 3);
  const int tileN = (xcd & 1) * 8 + (idx >> 2);
  const int rowA0 = tileM * BM;
  const int colB0 = tileN * BN;

  // Pre-swizzled staging sources. Thread stages A phys chunks {tid, 512+tid}
  // and B phys chunk {tid}; logical chunk = p ^ ((p>>3)&3).
  const int lc  = tid ^ ((tid >> 3) & 3);
  const int sr  = lc >> 2;   // 0..127
  const int sc  = lc & 3;
  const unsigned short* srcA = Abf + (size_t)(rowA0 + sr) * K_PAD + sc * 8;
  const unsigned short* srcB = Bbf + (size_t)(colB0 + sr) * K_PAD + sc * 8;

  // Read-side byte offset within a slot plane (swizzle folded in).
  const int laneOff = rl * 64 + ((g * 16) ^ (((rl >> 1) & 3) << 4));

#define GLOAD(dst, src)                                                         \
  __builtin_amdgcn_global_load_lds(                                             \
      (const __attribute__((address_space(1))) unsigned int*)(const void*)(src),\
      (__attribute__((address_space(3))) unsigned int*)(void*)(dst), 16, 0, 0)

  // Stage one ks-step (elements [koff, koff+32) of K) into slot j.
#define SLOT(j, koff)                                                           \
  do {                                                                          \
    char* _pa = (char*)&As[j][0];                                               \
    GLOAD(_pa + tid * 16, srcA + (koff));                                       \
    GLOAD(_pa + 8192 + tid * 16, srcA + (size_t)128 * K_PAD + (koff));          \
    GLOAD((char*)&Bs[j][0] + tid * 16, srcB + (koff));                          \
  } while (0)

#define LDFRAGS(j)                                                              \
  do {                                                                          \
    const char* _pa = (const char*)&As[j][0] + wm * 4096 + laneOff;             \
    av[0] = *(const bf16x8*)(_pa);                                              \
    av[1] = *(const bf16x8*)(_pa + 1024);                                       \
    av[2] = *(const bf16x8*)(_pa + 2048);                                       \
    av[3] = *(const bf16x8*)(_pa + 3072);                                       \
    const char* _pb = (const char*)&Bs[j][0] + wn * 4096 + laneOff;             \
    bv[0] = *(const bf16x8*)(_pb);                                              \
    bv[1] = *(const bf16x8*)(_pb + 1024);                                       \
    bv[2] = *(const bf16x8*)(_pb + 2048);                                       \
    bv[3] = *(const bf16x8*)(_pb + 3072);                                       \
  } while (0)

#define MFMA16()                                                                \
  do {                                                                          \
    __builtin_amdgcn_s_setprio(1);                                              \
    _Pragma("unroll") for (int _m = 0; _m < 4; ++_m)                            \
      _Pragma("unroll") for (int _n = 0; _n < 4; ++_n)                          \
        acc[_m][_n] = __builtin_amdgcn_mfma_f32_16x16x32_bf16(                  \
            av[_m], bv[_n], acc[_m][_n], 0, 0, 0);                              \
    __builtin_amdgcn_s_setprio(0);                                              \
  } while (0)

#define BAR() __builtin_amdgcn_s_barrier()
#define VMW(N) asm volatile("s_waitcnt vmcnt(" #N ")" ::: "memory")

  f32x4 acc[4][4];
#pragma unroll
  for (int m = 0; m < 4; ++m)
#pragma unroll
    for (int n = 0; n < 4; ++n) acc[m][n] = (f32x4)0.f;

  bf16x8 av[4], bv[4];

  // Prologue: slots 0..3 <- ks 0..3 (12 loads); wait for ks0 (oldest 3).
  SLOT(0, 0); SLOT(1, 32); SLOT(2, 64); SLOT(3, 96);
  VMW(9); BAR();

  int kb = 128;   // element offset of ks (s+4) when s = it*5
#pragma unroll 1
  for (int it = 0; it < 7; ++it) {   // phases s = it*5 .. it*5+4  (s = 0..34)
    SLOT(4, kb);       LDFRAGS(0); BAR(); MFMA16(); VMW(9); BAR();
    SLOT(0, kb + 32);  LDFRAGS(1); BAR(); MFMA16(); VMW(9); BAR();
    SLOT(1, kb + 64);  LDFRAGS(2); BAR(); MFMA16(); VMW(9); BAR();
    SLOT(2, kb + 96);  LDFRAGS(3); BAR(); MFMA16(); VMW(9); BAR();
    SLOT(3, kb + 128); LDFRAGS(4); BAR(); MFMA16(); VMW(9); BAR();
    kb += 160;
  }
  // Tail: s = 35..41 (kb == 1248 == ks39*32)
  SLOT(4, 1248); LDFRAGS(0); BAR(); MFMA16(); VMW(9); BAR();  // s=35 stage ks39
  SLOT(0, 1280); LDFRAGS(1); BAR(); MFMA16(); VMW(9); BAR();  // s=36 stage ks40
  SLOT(1, 1312); LDFRAGS(2); BAR(); MFMA16(); VMW(9); BAR();  // s=37 stage ks41
  LDFRAGS(3);                BAR(); MFMA16(); VMW(6); BAR();  // s=38
  LDFRAGS(4);                BAR(); MFMA16(); VMW(3); BAR();  // s=39
  LDFRAGS(0);                BAR(); MFMA16(); VMW(0); BAR();  // s=40 (ks40)
  LDFRAGS(1);                BAR(); MFMA16();                 // s=41 (ks41)

#undef GLOAD
#undef SLOT
#undef LDFRAGS
#undef MFMA16
#undef BAR
#undef VMW

  // Epilogue: wave's 64 rows = one batch (bidx = tileM*4 + wm).
  // acc[m][n] elem j = G(c = m*16 + g*4 + j, u = colB0 + wn*64 + n*16 + rl).
  const int bidx = tileM * 4 + wm;
  float vtmp[4];
#pragma unroll
  for (int n = 0; n < 4; ++n) {
    const int u = colB0 + wn * 64 + n * 16 + rl;
    const float* fwrow = fw + (size_t)u * NC;
    float s = 0.f;
#pragma unroll
    for (int m = 0; m < 4; ++m) {
      float4 w4 = *(const float4*)(fwrow + m * 16 + g * 4);
      f32x4 a_ = acc[m][n];
      s += w4.x * a_[0] + w4.y * a_[1] + w4.z * a_[2] + w4.w * a_[3];
    }
    s += __shfl_xor(s, 16, 64);   // reduce across k-groups (lanes ^16, ^32)
    s += __shfl_xor(s, 32, 64);
    vtmp[n] = s;
  }
  const int ucol = colB0 + wn * 64 + lane;
  float r = (g == 0) ? vtmp[0] : (g == 1) ? vtmp[1] : (g == 2) ? vtmp[2] : vtmp[3];
  out[(size_t)bidx * NU + ucol] = r + bias[ucol];
}

extern "C" void kernel_launch(void* const* d_in, const int* in_sizes, int n_in,
                              void* d_out, int out_size, void* d_ws, size_t ws_size,
                              hipStream_t stream) {
  const float* x    = (const float*)d_in[0];  // [64,64,36,36]
  const float* fw   = (const float*)d_in[1];  // [2048,64,1,1]
  const float* bias = (const float*)d_in[2];  // [2048]
  const float* sw   = (const float*)d_in[3];  // [2048,36,36]
  float* out = (float*)d_out;                 // [64][2048]

  unsigned short* Abf = (unsigned short*)d_ws;            // 4096*1344*2 B
  unsigned short* Bbf = Abf + (size_t)M_ROWS * K_PAD;     // 2048*1344*2 B

  // Convert + zero-pad both inputs to bf16 (K-major), one launch
  {
    int total = (M_ROWS + NU) * (K_PAD / 8);
    int blocks = (total + 255) / 256;
    if (blocks > 2048) blocks = 2048;
    convert_pad_kernel<<<blocks, 256, 0, stream>>>(x, sw, Abf);
  }

  // Fused GEMM + readout + bias: 16 M-tiles x 16 N-tiles = 256 blocks
  fused_readout_gemm<<<dim3(256), 512, 0, stream>>>(Abf, Bbf, fw, bias, out);
}

// Round 11
// 44.046 us; speedup vs baseline: 1.0195x; 1.0195x over previous
//
#include <hip/hip_runtime.h>
#include <hip/hip_bf16.h>
#include <stdint.h>

// Problem geometry
#define NB 64          // batch
#define NC 64          // C_IN
#define NU 2048        // N_UNITS
#define K_REAL 1296    // H*W = 36*36
#define K_PAD  1344    // 42 ks-steps of 32 (3.7% pad)
#define M_ROWS 4096    // NB*NC

// GEMM tile
#define BM 128
#define BN 128
#define NKS 42         // 32-wide K-steps

typedef __attribute__((ext_vector_type(4))) float f32x4;
typedef __attribute__((ext_vector_type(8))) short bf16x8;

__device__ __forceinline__ unsigned short f2bf_rne(float f) {
  union { float f; uint32_t u; } v; v.f = f;
  uint32_t u = v.u;
  return (unsigned short)((u + 0x7FFFu + ((u >> 16) & 1u)) >> 16);
}

// Convert fp32 [rows][K_REAL] -> bf16 [rows][K_PAD], zero-filling the pad
// tail. Handles BOTH x (rows 0..4095) and sw (rows 4096..6143) in one launch.
__global__ void convert_pad_kernel(const float* __restrict__ x,
                                   const float* __restrict__ sw,
                                   unsigned short* __restrict__ dst) {
  const int KB = K_PAD / 8;  // 168 8-element blocks per row
  const int total = (M_ROWS + NU) * KB;
  for (int idx = blockIdx.x * blockDim.x + threadIdx.x; idx < total;
       idx += gridDim.x * blockDim.x) {
    int r  = idx / KB;
    int kb = idx - r * KB;
    int k0 = kb * 8;
    uint32_t p0 = 0, p1 = 0, p2 = 0, p3 = 0;
    if (k0 + 8 <= K_REAL) {  // K_REAL % 8 == 0: blocks are all-real or all-pad
      const float* srow = (r < M_ROWS) ? (x + (size_t)r * K_REAL)
                                       : (sw + (size_t)(r - M_ROWS) * K_REAL);
      const float4* s = (const float4*)(srow + k0);
      float4 f0 = s[0];
      float4 f1 = s[1];
      p0 = (uint32_t)f2bf_rne(f0.x) | ((uint32_t)f2bf_rne(f0.y) << 16);
      p1 = (uint32_t)f2bf_rne(f0.z) | ((uint32_t)f2bf_rne(f0.w) << 16);
      p2 = (uint32_t)f2bf_rne(f1.x) | ((uint32_t)f2bf_rne(f1.y) << 16);
      p3 = (uint32_t)f2bf_rne(f1.z) | ((uint32_t)f2bf_rne(f1.w) << 16);
    }
    uint4 o; o.x = p0; o.y = p1; o.z = p2; o.w = p3;
    *(uint4*)(dst + (size_t)r * K_PAD + k0) = o;
  }
}

// ---------------------------------------------------------------------------
// 128x128 fused GEMM, ring-of-4 ks-slot pipeline, 2 BLOCKS PER CU (R11).
// Same 8-phase counted-vmcnt schedule as R8/R9, but block halved so two
// independent barrier domains co-reside per CU: one block's MFMA/ds_read
// fills the other's barrier + lgkm latency gaps (m114 wave-overlap).
// 4 waves = 2M x 2N; per wave 4x4 16x16x32 frags (64 AGPR acc).
// LDS 64KB: 4 slots x (A[128x32] 8KB + B[128x32] 8KB).
// Phase s: { stage ks s+3 -> slot (s+3)%4 | ds_read frags slot s%4
//            -> s_barrier -> 16 MFMA (setprio) -> vmcnt(8) -> s_barrier }.
// SLOT = 4 gload_lds; vmcnt(8) = 2 slots outstanding; slot s+1 (staged at
// s-2) guaranteed landed. Overwrite-safety: slot (s+3)%4 == (s-1)%4 was
// last read in phase s-1; reads drained before its closing barrier; stage
// issues after. Tail: VMW 8,8,8,4,0.
// Swizzle (16B chunks, involution): phys chunk p holds logical p^((p>>3)&3);
// read addr byte = row*64 + (g*16 ^ (((rl>>1)&3)<<4)).  (0 conflicts R5-R10.)
// XCD mapping: 8 tileM x 8 tileN rectangle per XCD (64 of 512 blocks).
// ---------------------------------------------------------------------------
__global__ __launch_bounds__(256)
void fused_readout_gemm(const unsigned short* __restrict__ Abf,  // [M_ROWS][K_PAD]
                        const unsigned short* __restrict__ Bbf,  // [NU][K_PAD]
                        const float* __restrict__ fw,            // [NU][NC]
                        const float* __restrict__ bias,          // [NU]
                        float* __restrict__ out) {               // [NB][NU]
  __shared__ unsigned short As[4][4096];  // slot: 128 rows x 32 (8KB)
  __shared__ unsigned short Bs[4][4096];  // slot: 128 rows x 32 (8KB)

  const int tid  = threadIdx.x;
  const int lane = tid & 63;
  const int w    = tid >> 6;    // 0..3
  const int wm   = w >> 1;      // 0..1: 64-row group (one batch each)
  const int wn   = w & 1;       // 0..1: 64-col group
  const int g    = lane >> 4;   // k-group 0..3
  const int rl   = lane & 15;

  // XCD mapping: xcd = braw&7 owns an 8(tileM) x 8(tileN) rectangle.
  const int braw  = (int)blockIdx.x;
  const int xcd   = braw & 7;
  const int idx   = braw >> 3;           // 0..63
  const int tileM = (xcd >> 1) * 8 + (idx & 7);    // 0..31
  const int tileN = (xcd & 1) * 8 + (idx >> 3);    // 0..15
  const int rowA0 = tileM * BM;
  const int colB0 = tileN * BN;

  // Pre-swizzled staging sources. Thread stages phys chunks {tid, 256+tid}
  // of each 512-chunk plane; logical chunk = p ^ ((p>>3)&3) (256 offset
  // doesn't disturb bits 0-4 -> second chunk is just row +64).
  const int lc  = tid ^ ((tid >> 3) & 3);
  const int sr  = lc >> 2;   // 0..63
  const int sc  = lc & 3;
  const unsigned short* srcA = Abf + (size_t)(rowA0 + sr) * K_PAD + sc * 8;
  const unsigned short* srcB = Bbf + (size_t)(colB0 + sr) * K_PAD + sc * 8;

  // Read-side byte offset within a slot plane (swizzle folded in).
  const int laneOff = rl * 64 + ((g * 16) ^ (((rl >> 1) & 3) << 4));

#define GLOAD(dst, src)                                                         \
  __builtin_amdgcn_global_load_lds(                                             \
      (const __attribute__((address_space(1))) unsigned int*)(const void*)(src),\
      (__attribute__((address_space(3))) unsigned int*)(void*)(dst), 16, 0, 0)

  // Stage one ks-step (elements [koff, koff+32) of K) into slot j: 4 loads.
#define SLOT(j, koff)                                                           \
  do {                                                                          \
    char* _pa = (char*)&As[j][0];                                               \
    GLOAD(_pa + tid * 16, srcA + (koff));                                       \
    GLOAD(_pa + 4096 + tid * 16, srcA + (size_t)64 * K_PAD + (koff));           \
    char* _pb = (char*)&Bs[j][0];                                               \
    GLOAD(_pb + tid * 16, srcB + (koff));                                       \
    GLOAD(_pb + 4096 + tid * 16, srcB + (size_t)64 * K_PAD + (koff));           \
  } while (0)

#define LDFRAGS(j)                                                              \
  do {                                                                          \
    const char* _pa = (const char*)&As[j][0] + wm * 4096 + laneOff;             \
    av[0] = *(const bf16x8*)(_pa);                                              \
    av[1] = *(const bf16x8*)(_pa + 1024);                                       \
    av[2] = *(const bf16x8*)(_pa + 2048);                                       \
    av[3] = *(const bf16x8*)(_pa + 3072);                                       \
    const char* _pb = (const char*)&Bs[j][0] + wn * 4096 + laneOff;             \
    bv[0] = *(const bf16x8*)(_pb);                                              \
    bv[1] = *(const bf16x8*)(_pb + 1024);                                       \
    bv[2] = *(const bf16x8*)(_pb + 2048);                                       \
    bv[3] = *(const bf16x8*)(_pb + 3072);                                       \
  } while (0)

#define MFMA16()                                                                \
  do {                                                                          \
    __builtin_amdgcn_s_setprio(1);                                              \
    _Pragma("unroll") for (int _m = 0; _m < 4; ++_m)                            \
      _Pragma("unroll") for (int _n = 0; _n < 4; ++_n)                          \
        acc[_m][_n] = __builtin_amdgcn_mfma_f32_16x16x32_bf16(                  \
            av[_m], bv[_n], acc[_m][_n], 0, 0, 0);                              \
    __builtin_amdgcn_s_setprio(0);                                              \
  } while (0)

#define BAR()                                                                   \
  do { __builtin_amdgcn_s_barrier(); __builtin_amdgcn_sched_barrier(0); } while (0)
#define VMW(N)                                                                  \
  do { asm volatile("s_waitcnt vmcnt(" #N ")" ::: "memory");                    \
       __builtin_amdgcn_sched_barrier(0); } while (0)

  f32x4 acc[4][4];
#pragma unroll
  for (int m = 0; m < 4; ++m)
#pragma unroll
    for (int n = 0; n < 4; ++n) acc[m][n] = (f32x4)0.f;

  bf16x8 av[4], bv[4];

  // Prologue: slots 0..2 <- ks 0..2 (12 loads); wait for ks0 (oldest 4).
  SLOT(0, 0); SLOT(1, 32); SLOT(2, 64);
  VMW(8); BAR();

  int kb = 96;   // element offset of ks (s+3) at s = 4*it
#pragma unroll 1
  for (int it = 0; it < 9; ++it) {   // phases s = 4it .. 4it+3  (s = 0..35)
    SLOT(3, kb);      LDFRAGS(0); BAR(); MFMA16(); VMW(8); BAR();
    SLOT(0, kb + 32); LDFRAGS(1); BAR(); MFMA16(); VMW(8); BAR();
    SLOT(1, kb + 64); LDFRAGS(2); BAR(); MFMA16(); VMW(8); BAR();
    SLOT(2, kb + 96); LDFRAGS(3); BAR(); MFMA16(); VMW(8); BAR();
    kb += 128;
  }
  // Tail: s = 36..41 (kb == 1248 == ks39*32)
  SLOT(3, 1248); LDFRAGS(0); BAR(); MFMA16(); VMW(8); BAR();  // s=36 stage ks39
  SLOT(0, 1280); LDFRAGS(1); BAR(); MFMA16(); VMW(8); BAR();  // s=37 stage ks40
  SLOT(1, 1312); LDFRAGS(2); BAR(); MFMA16(); VMW(8); BAR();  // s=38 stage ks41
  LDFRAGS(3);                BAR(); MFMA16(); VMW(4); BAR();  // s=39
  LDFRAGS(0);                BAR(); MFMA16(); VMW(0); BAR();  // s=40
  LDFRAGS(1);                BAR(); MFMA16();                 // s=41

#undef GLOAD
#undef SLOT
#undef LDFRAGS
#undef MFMA16
#undef BAR
#undef VMW

  // Epilogue: wave's 64 rows = one batch (bidx = tileM*2 + wm).
  // acc[m][n] elem j = G(c = m*16 + g*4 + j, u = colB0 + wn*64 + n*16 + rl).
  const int bidx = tileM * 2 + wm;
  float vtmp[4];
#pragma unroll
  for (int n = 0; n < 4; ++n) {
    const int u = colB0 + wn * 64 + n * 16 + rl;
    const float* fwrow = fw + (size_t)u * NC;
    float s = 0.f;
#pragma unroll
    for (int m = 0; m < 4; ++m) {
      float4 w4 = *(const float4*)(fwrow + m * 16 + g * 4);
      f32x4 a_ = acc[m][n];
      s += w4.x * a_[0] + w4.y * a_[1] + w4.z * a_[2] + w4.w * a_[3];
    }
    s += __shfl_xor(s, 16, 64);   // reduce across k-groups (lanes ^16, ^32)
    s += __shfl_xor(s, 32, 64);
    vtmp[n] = s;
  }
  const int ucol = colB0 + wn * 64 + lane;
  float r = (g == 0) ? vtmp[0] : (g == 1) ? vtmp[1] : (g == 2) ? vtmp[2] : vtmp[3];
  out[(size_t)bidx * NU + ucol] = r + bias[ucol];
}

extern "C" void kernel_launch(void* const* d_in, const int* in_sizes, int n_in,
                              void* d_out, int out_size, void* d_ws, size_t ws_size,
                              hipStream_t stream) {
  const float* x    = (const float*)d_in[0];  // [64,64,36,36]
  const float* fw   = (const float*)d_in[1];  // [2048,64,1,1]
  const float* bias = (const float*)d_in[2];  // [2048]
  const float* sw   = (const float*)d_in[3];  // [2048,36,36]
  float* out = (float*)d_out;                 // [64][2048]

  unsigned short* Abf = (unsigned short*)d_ws;            // 4096*1344*2 B
  unsigned short* Bbf = Abf + (size_t)M_ROWS * K_PAD;     // 2048*1344*2 B

  // Convert + zero-pad both inputs to bf16 (K-major), one launch
  {
    int total = (M_ROWS + NU) * (K_PAD / 8);
    int blocks = (total + 255) / 256;
    if (blocks > 2048) blocks = 2048;
    convert_pad_kernel<<<blocks, 256, 0, stream>>>(x, sw, Abf);
  }

  // Fused GEMM + readout + bias: 32 M-tiles x 16 N-tiles = 512 blocks (2/CU)
  fused_readout_gemm<<<dim3(512), 256, 0, stream>>>(Abf, Bbf, fw, bias, out);
}